// Round 8
// baseline (204.595 us; speedup 1.0000x reference)
//
#include <hip/hip_runtime.h>

#define N_NODES 100000
#define N_EDGES 600000
#define D 128
#define MAXDEG 64
#define OVF_CAP 4096
#define BM 16              // nodes per block in k_gemm

typedef __attribute__((ext_vector_type(8))) short bf16x8;
typedef __attribute__((ext_vector_type(4))) float f32x4;

static __device__ inline ushort f2bf(float f) {
    unsigned x = __float_as_uint(f);
    unsigned r = (x + 0x7fffu + ((x >> 16) & 1u)) >> 16;  // RNE
    return (ushort)r;
}
static __device__ inline f32x4 nt_load4(const float* p) {
    return __builtin_nontemporal_load((const f32x4*)p);
}
static __device__ inline ushort4 pack4(f32x4 v) {
    ushort4 u;
    u.x = f2bf(v[0]); u.y = f2bf(v[1]); u.z = f2bf(v[2]); u.w = f2bf(v[3]);
    return u;
}

// ws layout (byte offsets):
//   0         Wfrag  ushort[512*128]   bf16 fused weight, MFMA B-frag order
//   131072    Wcat32 float[512*128]    fp32 fused weight (overflow path)
//   393216    bv     float[128]
//   393728    deg    float[N]
//   793728    cnt    int[N+1] (+pad)
//   1193744   ovf    int[OVF_CAP]
//   1210128   elist2 int2[N*MAXDEG]
//   52410128  Sea16  ushort[N*256]     per-node [S | Ea] bf16
//
// out[n] = [h[n] | S[n] | deg[n]*h[n] | Ea[n]] @ Wcat + deg[n]*bv + b_upd
// Wfrag[(kb*8+cb)*512 + l*8 + i] = Wcat[kb*32+(l>>4)*8+i][cb*16+(l&15)]
// Wcat rows: 0..127 = Wu1; 128..255 = W1@Wu2; 256..383 = W2@Wu2; 384..511 = W3@Wu2
// bv = b_msg @ Wu2

__global__ void k_zero(int* __restrict__ cnt) {
    int i = blockIdx.x * 256 + threadIdx.x;
    if (i < N_NODES + 1) cnt[i] = 0;
}

__global__ void k_build_w(const float* __restrict__ W_msg,
                          const float* __restrict__ b_msg,
                          const float* __restrict__ W_upd,
                          ushort* __restrict__ Wfrag,
                          float* __restrict__ Wcat32,
                          float* __restrict__ bv)
{
    int gid = blockIdx.x * 256 + threadIdx.x;
    if (gid < 512 * 128) {
        int i = gid & 7;
        int l = (gid >> 3) & 63;
        int fb = gid >> 9;          // kb*8 + cb
        int kb = fb >> 3, cb = fb & 7;
        int k = kb * 32 + ((l >> 4) * 8) + i;
        int j = cb * 16 + (l & 15);
        float acc;
        if (k < 128) {
            acc = W_upd[k * 128 + j];
        } else {
            int r = k - 128;
            acc = 0.f;
            #pragma unroll 4
            for (int dd = 0; dd < 128; ++dd)
                acc += W_msg[r * 128 + dd] * W_upd[(128 + dd) * 128 + j];
        }
        Wfrag[gid] = f2bf(acc);
        Wcat32[k * 128 + j] = acc;
    } else if (gid < 512 * 128 + 128) {
        int j = gid - 512 * 128;
        float acc = 0.f;
        for (int dd = 0; dd < 128; ++dd)
            acc += b_msg[dd] * W_upd[(128 + dd) * 128 + j];
        bv[j] = acc;
    }
}

__global__ void k_bucket(const int* __restrict__ eidx,
                         int* __restrict__ cnt,
                         int* __restrict__ ovf,
                         int2* __restrict__ elist2)
{
    int e = blockIdx.x * 256 + threadIdx.x;
    if (e >= N_EDGES) return;
    int s = eidx[e];
    int r = eidx[N_EDGES + e];
    int slot = atomicAdd(cnt + r, 1);
    if (slot < MAXDEG) {
        elist2[(size_t)r * MAXDEG + slot] = make_int2(e, s);
    } else {
        int p = atomicAdd(cnt + N_NODES, 1);
        if (p < OVF_CAP) ovf[p] = e;
    }
}

// Barrier-free gather: each HALF-WAVE owns one node (2 nodes/wave, two
// independent load chains). 32 lanes x float4 = full 512B row per instruction.
// Writes Sea16[n] = [S | Ea] bf16 + deg[n]. No LDS, no __syncthreads.
__global__ __launch_bounds__(256, 8) void k_gather3(
    const float* __restrict__ h,
    const float* __restrict__ ea,
    const int* __restrict__ cnt,
    const int2* __restrict__ elist2,
    ushort* __restrict__ Sea16,
    float* __restrict__ deg)
{
    int gid = blockIdx.x * 256 + threadIdx.x;
    int w = gid >> 6;
    if (w >= N_NODES / 2) return;
    const int lane = gid & 63;
    const int half = lane >> 5;
    const int hl = lane & 31;
    const int n = 2 * w + half;          // this half-wave's node

    const int c = cnt[n];
    const int m = c < MAXDEG ? c : MAXDEG;
    // preload first 32 edge slots (covers P(deg<=32) ~ 1-1e-15)
    int2 es = elist2[(size_t)n * MAXDEG + hl];

    f32x4 aS = {0.f, 0.f, 0.f, 0.f};
    f32x4 aE = {0.f, 0.f, 0.f, 0.f};
    int t = 0;
    for (; t + 2 <= m; t += 2) {
        int e0, s0, e1, s1;
        if (t + 1 < 32) {
            e0 = __shfl(es.x, half * 32 + t);     s0 = __shfl(es.y, half * 32 + t);
            e1 = __shfl(es.x, half * 32 + t + 1); s1 = __shfl(es.y, half * 32 + t + 1);
        } else {
            int2 p0 = elist2[(size_t)n * MAXDEG + t];
            int2 p1 = elist2[(size_t)n * MAXDEG + t + 1];
            e0 = p0.x; s0 = p0.y; e1 = p1.x; s1 = p1.y;
        }
        f32x4 a0 = *(const f32x4*)(h + (size_t)s0 * D + hl * 4);
        f32x4 b0 = nt_load4(ea + (size_t)e0 * D + hl * 4);
        f32x4 a1 = *(const f32x4*)(h + (size_t)s1 * D + hl * 4);
        f32x4 b1 = nt_load4(ea + (size_t)e1 * D + hl * 4);
        aS += a0 + a1;
        aE += b0 + b1;
    }
    if (t < m) {
        int e0, s0;
        if (t < 32) {
            e0 = __shfl(es.x, half * 32 + t); s0 = __shfl(es.y, half * 32 + t);
        } else {
            int2 p0 = elist2[(size_t)n * MAXDEG + t];
            e0 = p0.x; s0 = p0.y;
        }
        aS += *(const f32x4*)(h + (size_t)s0 * D + hl * 4);
        aE += nt_load4(ea + (size_t)e0 * D + hl * 4);
    }

    *(ushort4*)(Sea16 + (size_t)n * 256 +       hl * 4) = pack4(aS);
    *(ushort4*)(Sea16 + (size_t)n * 256 + 128 + hl * 4) = pack4(aE);
    if (hl == 0) deg[n] = (float)c;
}

// Streaming MFMA GEMM: X=[h|S|deg*h|Ea] (bf16) @ Wfrag. BM=16 nodes/block.
__global__ __launch_bounds__(256, 8) void k_gemm(
    const float* __restrict__ h,
    const ushort* __restrict__ Sea16,
    const float* __restrict__ deg,
    const ushort* __restrict__ Wfrag,
    const float* __restrict__ bv,
    const float* __restrict__ b_upd,
    float* __restrict__ out)
{
    __shared__ ushort Xs[BM][520];
    __shared__ float degL[BM];
    const int tid = threadIdx.x;
    const int n0 = blockIdx.x * BM;
    if (tid < BM) degL[tid] = deg[n0 + tid];

    for (int q = tid; q < BM * 64; q += 256) {
        int i = q >> 6, j = q & 63;   // j = ushort8 chunk of the 512-col row
        int n = n0 + i;
        if (j < 16) {
            f32x4 v0 = *(const f32x4*)(h + (size_t)n * D + j * 8);
            f32x4 v1 = *(const f32x4*)(h + (size_t)n * D + j * 8 + 4);
            *(ushort4*)&Xs[i][j * 8]     = pack4(v0);
            *(ushort4*)&Xs[i][j * 8 + 4] = pack4(v1);
        } else if (j < 32) {
            uint4 v = *(const uint4*)(Sea16 + (size_t)n * 256 + (j - 16) * 8);
            *(uint4*)&Xs[i][j * 8] = v;
        } else if (j < 48) {
            float dv = deg[n];
            f32x4 v0 = *(const f32x4*)(h + (size_t)n * D + (j - 32) * 8);
            f32x4 v1 = *(const f32x4*)(h + (size_t)n * D + (j - 32) * 8 + 4);
            v0 *= dv; v1 *= dv;
            *(ushort4*)&Xs[i][j * 8]     = pack4(v0);
            *(ushort4*)&Xs[i][j * 8 + 4] = pack4(v1);
        } else {
            uint4 v = *(const uint4*)(Sea16 + (size_t)n * 256 + 128 + (j - 48) * 8);
            *(uint4*)&Xs[i][j * 8] = v;
        }
    }
    __syncthreads();

    const int lane = tid & 63;
    const int wv = tid >> 6;
    const int arow = lane & 15;
    const int koff = (lane >> 4) * 8;

    f32x4 acc[2] = {};
    for (int kb = 0; kb < 16; ++kb) {
        bf16x8 a = *(const bf16x8*)&Xs[arow][kb * 32 + koff];
        #pragma unroll
        for (int cc = 0; cc < 2; ++cc) {
            int fb = kb * 8 + wv * 2 + cc;
            bf16x8 b = *(const bf16x8*)(Wfrag + ((size_t)fb * 64 + lane) * 8);
            acc[cc] = __builtin_amdgcn_mfma_f32_16x16x32_bf16(a, b, acc[cc], 0, 0, 0);
        }
    }

    const int r0 = (lane >> 4) * 4;
    #pragma unroll
    for (int cc = 0; cc < 2; ++cc) {
        int col = wv * 32 + cc * 16 + (lane & 15);
        float bvv = bv[col];
        float buv = b_upd[col];
        #pragma unroll
        for (int r = 0; r < 4; ++r) {
            int rl = r0 + r;
            out[(size_t)(n0 + rl) * D + col] = acc[cc][r] + degL[rl] * bvv + buv;
        }
    }
}

// Overflow edges (expected 0): add h_s@(W1@Wu2) + ea@(W3@Wu2) into out[rec].
__global__ void k_ovf(const float* __restrict__ h,
                      const int* __restrict__ eidx,
                      const float* __restrict__ ea,
                      const int* __restrict__ cnt,
                      const int* __restrict__ ovf,
                      const float* __restrict__ Wcat32,
                      float* __restrict__ out)
{
    int ncnt = cnt[N_NODES];
    if (ncnt > OVF_CAP) ncnt = OVF_CAP;
    if (ncnt <= 0) return;
    int lane = threadIdx.x & 63;
    int w = threadIdx.x >> 6;
    for (int i = w; i < ncnt; i += 4) {
        int e = ovf[i];
        int s = eidx[e];
        int r = eidx[N_EDGES + e];
        float acc0 = 0.f, acc1 = 0.f;
        for (int dd = 0; dd < 128; ++dd) {
            float hs = h[(size_t)s * D + dd];
            float ev = ea[(size_t)e * D + dd];
            acc0 += hs * Wcat32[(128 + dd) * 128 + lane * 2]     + ev * Wcat32[(384 + dd) * 128 + lane * 2];
            acc1 += hs * Wcat32[(128 + dd) * 128 + lane * 2 + 1] + ev * Wcat32[(384 + dd) * 128 + lane * 2 + 1];
        }
        atomicAdd(out + (size_t)r * D + lane * 2 + 0, acc0);
        atomicAdd(out + (size_t)r * D + lane * 2 + 1, acc1);
    }
}

extern "C" void kernel_launch(void* const* d_in, const int* in_sizes, int n_in,
                              void* d_out, int out_size, void* d_ws, size_t ws_size,
                              hipStream_t stream)
{
    const float* h     = (const float*)d_in[0];
    const int*   eidx  = (const int*)d_in[1];
    const float* eattr = (const float*)d_in[2];
    const float* W_msg = (const float*)d_in[3];
    const float* b_msg = (const float*)d_in[4];
    const float* W_upd = (const float*)d_in[5];
    const float* b_upd = (const float*)d_in[6];
    float* out = (float*)d_out;

    char* base = (char*)d_ws;
    ushort* Wfrag  = (ushort*)(base);
    float*  Wcat32 = (float*)(base + 131072);
    float*  bv     = (float*)(base + 393216);
    float*  deg    = (float*)(base + 393728);
    int*    cnt    = (int*)(base + 793728);
    int*    ovf    = (int*)(base + 1193744);
    int2*   elist2 = (int2*)(base + 1210128);
    ushort* Sea16  = (ushort*)(base + 52410128);

    k_zero<<<(N_NODES + 1 + 255) / 256, 256, 0, stream>>>(cnt);
    k_build_w<<<(512 * 128 + 128 + 255) / 256, 256, 0, stream>>>(W_msg, b_msg, W_upd, Wfrag, Wcat32, bv);
    k_bucket<<<(N_EDGES + 255) / 256, 256, 0, stream>>>(eidx, cnt, ovf, elist2);
    k_gather3<<<(N_NODES / 2 * 64) / 256, 256, 0, stream>>>(h, eattr, cnt, elist2, Sea16, deg);
    k_gemm<<<N_NODES / BM, 256, 0, stream>>>(h, Sea16, deg, Wfrag, bv, b_upd, out);
    k_ovf<<<1, 256, 0, stream>>>(h, eidx, eattr, cnt, ovf, Wcat32, out);
}